// Round 1
// baseline (644.055 us; speedup 1.0000x reference)
//
#include <hip/hip_runtime.h>
#include <cstdint>
#include <cstddef>

// ---------------------------------------------------------------------------
// KAN encode: x(4096,1024) -> KANLinear(1024->2048) -> KANLinear(2048->1024)
//             -> ReLU -> Dense(1024->512)+bias
// bf16 MFMA GEMMs over augmented K (9 channels per input feature).
// R8: replace the 2-barrier m97-style gemm_big (827 TF, MfmaUtil 35%) with an
//     8-phase counted-vmcnt schedule (T3+T4+T5):
//       - 256x256 tile, 512 thr = 8 waves (2M x 4N), 128x64 per wave
//       - K in 32-slabs, 4-deep cyclic LDS buffering (A,W: 4 x [256][32] each
//         = 128 KiB), stage slab s+3 while computing slab s
//       - raw s_barrier + s_waitcnt vmcnt(8) once per slab (never 0 in loop),
//         epilogue drains 8 -> 4 -> 0
//       - s_setprio(1) around each 16-MFMA cluster
//       - proven 0-conflict XOR swizzle q = p ^ ((r>>1)&3) kept as-is
//     Split-K keeps 256 blocks (= 1/CU exactly): L0 z=2, L1 z=4.
// ---------------------------------------------------------------------------

typedef __bf16 bf16x8 __attribute__((ext_vector_type(8)));
typedef float floatx4 __attribute__((ext_vector_type(4)));

#define BATCH 4096
#define DIN   1024
#define H0N   2048
#define H1N   1024
#define LOUT  512

// Workspace layout (bytes). Total = 227,540,992.
#define OFF_A0  ((size_t)0)           // bf16 4096*9216  = 75,497,472
#define OFF_W0  ((size_t)75497472)    // bf16 2048*9216  = 37,748,736
#define OFF_A1  ((size_t)0)           // bf16 4096*18432 = 150,994,944 (overlays A0+W0)
#define OFF_P0  ((size_t)150994944)   // f32 2*4096*2048 = 67,108,864
#define OFF_W1  ((size_t)218103808)   // bf16 1024*18432 = 37,748,736
#define OFF_P1  ((size_t)150994944)   // f32 4*4096*1024 = 67,108,864 (overlays P0)
#define OFF_H1R ((size_t)218103808)   // bf16 4096*1024  =  8,388,608 (overlays W1)
#define OFF_DW  ((size_t)226492416)   // bf16 512*1024   =  1,048,576

// --------------------------- spline bases ----------------------------------
__device__ __forceinline__ void bspline8(float x, float* out) {
    float b[11];
#pragma unroll
    for (int j = 0; j < 11; ++j) {
        float t0 = (j - 3) * 0.4f - 1.0f;
        float t1 = (j - 2) * 0.4f - 1.0f;
        b[j] = (x >= t0 && x < t1) ? 1.0f : 0.0f;
    }
#pragma unroll
    for (int k = 1; k <= 3; ++k) {
#pragma unroll
        for (int j = 0; j + k < 11; ++j) {
            float tj   = (j - 3) * 0.4f - 1.0f;
            float tj1  = (j - 2) * 0.4f - 1.0f;
            float tjk  = (j + k - 3) * 0.4f - 1.0f;
            float tjk1 = (j + k - 2) * 0.4f - 1.0f;
            float left  = (x - tj)   * (1.0f / (tjk - tj));
            float right = (tjk1 - x) * (1.0f / (tjk1 - tj1));
            b[j] = left * b[j] + right * b[j + 1];
        }
    }
#pragma unroll
    for (int j = 0; j < 8; ++j) out[j] = b[j];
}

// Store 256 threads * 9 bf16 via LDS as 288 coalesced 16B chunks.
__device__ __forceinline__ void coalesced_store9(__bf16* block_dst, const __bf16* vals) {
    __shared__ __bf16 sbuf[256 * 9];
    __bf16* p = &sbuf[threadIdx.x * 9];
#pragma unroll
    for (int j = 0; j < 9; ++j) p[j] = vals[j];
    __syncthreads();
    const uint4* src = (const uint4*)sbuf;
    uint4* dst = (uint4*)block_dst;
    dst[threadIdx.x] = src[threadIdx.x];
    if (threadIdx.x < 32) dst[256 + threadIdx.x] = src[256 + threadIdx.x];
}

__device__ __forceinline__ void act9(float v, __bf16* r) {
    float s = v / (1.0f + __expf(-v));
    float bb[8];
    bspline8(v, bb);
    r[0] = (__bf16)s;
#pragma unroll
    for (int j = 0; j < 8; ++j) r[1 + j] = (__bf16)bb[j];
}

__global__ void kan_act(const float* __restrict__ in, __bf16* __restrict__ out) {
    int base = blockIdx.x * 256;
    float v = in[base + threadIdx.x];
    __bf16 r[9];
    act9(v, r);
    coalesced_store9(out + (size_t)base * 9, r);
}

__global__ void kan_act_sum2(const float* __restrict__ pa, const float* __restrict__ pb,
                             __bf16* __restrict__ out) {
    int base = blockIdx.x * 256;
    int idx = base + threadIdx.x;
    float v = pa[idx] + pb[idx];
    __bf16 r[9];
    act9(v, r);
    coalesced_store9(out + (size_t)base * 9, r);
}

__global__ void relu_sum4(const float* __restrict__ p, size_t stride,
                          __bf16* __restrict__ out, int total4) {
    int idx = blockIdx.x * 256 + threadIdx.x;
    if (idx >= total4) return;
    const float4* p0 = (const float4*)p;
    const float4* p1 = (const float4*)(p + stride);
    const float4* p2 = (const float4*)(p + 2 * stride);
    const float4* p3 = (const float4*)(p + 3 * stride);
    float4 a = p0[idx], b = p1[idx], c = p2[idx], d = p3[idx];
    __bf16 r[4];
    r[0] = (__bf16)fmaxf(a.x + b.x + c.x + d.x, 0.0f);
    r[1] = (__bf16)fmaxf(a.y + b.y + c.y + d.y, 0.0f);
    r[2] = (__bf16)fmaxf(a.z + b.z + c.z + d.z, 0.0f);
    r[3] = (__bf16)fmaxf(a.w + b.w + c.w + d.w, 0.0f);
    *(uint2*)&out[(size_t)idx * 4] = *(uint2*)r;
}

__global__ void kan_wprep(const float* __restrict__ bw, const float* __restrict__ sw,
                          const float* __restrict__ ss, __bf16* __restrict__ out) {
    int base = blockIdx.x * 256;
    int idx = base + threadIdx.x;
    float b  = bw[idx];
    float sc = ss[idx];
    const float4* sv = (const float4*)(sw + (size_t)idx * 8);
    float4 a = sv[0], c = sv[1];
    __bf16 r[9];
    r[0] = (__bf16)b;
    r[1] = (__bf16)(a.x * sc); r[2] = (__bf16)(a.y * sc);
    r[3] = (__bf16)(a.z * sc); r[4] = (__bf16)(a.w * sc);
    r[5] = (__bf16)(c.x * sc); r[6] = (__bf16)(c.y * sc);
    r[7] = (__bf16)(c.z * sc); r[8] = (__bf16)(c.w * sc);
    coalesced_store9(out + (size_t)base * 9, r);
}

__global__ void f2bf(const float* __restrict__ in, __bf16* __restrict__ out,
                     int total) {
    int idx = blockIdx.x * 256 + threadIdx.x;
    if (idx < total) out[idx] = (__bf16)in[idx];
}

// --------------------------- staging helper --------------------------------
__device__ __forceinline__ void gload_lds16(const void* g, void* l) {
    __builtin_amdgcn_global_load_lds(
        (const __attribute__((address_space(1))) uint32_t*)g,
        (__attribute__((address_space(3))) uint32_t*)l, 16, 0, 0);
}

// Bank swizzle: LDS slot (row r, pos p) holds global chunk q = p ^ ((r>>1)&3).
// Frag reads (rows base+lr, lr=0..15, chunk kq) land 2 lanes per 4-bank group
// -> 2-way aliasing = free (verified: SQ_LDS_BANK_CONFLICT == 0).

// ------------- 8-phase counted-vmcnt MFMA GEMM: 256x256, 8 waves -----------
// C(M,N) = A(M,K) @ W(N,K)^T, bf16 in, fp32 out (split-K partial per z).
// K consumed in 32-slabs; LDS holds 4 slabs of A and 4 of W (cyclic).
// Pipeline: while computing slab s, stage slab s+3 into LDS slot (s+3)&3
// (= slot of slab s-1, whose last reads finished >=1 barrier + 16 MFMA +
//  >=200cyc DMA latency earlier). Per-wave loads: 4/slab (2 A in phase 0,
// 2 W in phase 1) -> steady-state wait vmcnt(8) once per slab.
__global__ __launch_bounds__(512, 2) void gemm8(
    const __bf16* __restrict__ A, const __bf16* __restrict__ W,
    float* __restrict__ Cout, int M, int N, int K, int Ks) {
    constexpr int SLAB = 256 * 32;            // elems per slab (16 KB)
    __shared__ __bf16 As[4 * SLAB];           // 64 KB
    __shared__ __bf16 Ws[4 * SLAB];           // 64 KB

    const int tid  = threadIdx.x;
    const int lane = tid & 63;
    const int wave = tid >> 6;                // 0..7
    const int wr   = wave >> 2;               // wave row  (0..1) -> 128 rows
    const int wc   = wave & 3;                // wave col  (0..3) -> 64 cols

    // XCD-aware swizzle (round-robin dispatch: id&7 = XCD); 256 blocks, 1/CU
    const int id    = (blockIdx.z * gridDim.y + blockIdx.y) * gridDim.x + blockIdx.x;
    const int mslab = gridDim.y >> 3;
    const int xcd   = id & 7;
    const int local = id >> 3;
    const int m_off = local % mslab;
    const int rest  = local / mslab;
    const int ntile = rest % gridDim.x;
    const int zt    = rest / gridDim.x;
    const int bm    = (xcd * mslab + m_off) * 256;
    const int bn    = ntile * 256;
    const int kbase = zt * Ks;
    const int NKs   = Ks >> 5;                // 32-wide slabs

    // ---- staging addressing: wave w owns LDS rows w*32 .. w*32+31 ----------
    const int sr0 = wave * 32 + (lane >> 2);         // load 0: rows +0..15
    const int sr1 = sr0 + 16;                        // load 1: rows +16..31
    const int q0  = (lane & 3) ^ ((sr0 >> 1) & 3);   // swizzled source chunk
    const int q1  = (lane & 3) ^ ((sr1 >> 1) & 3);
    const __bf16* pa0 = A + (size_t)(bm + sr0) * K + kbase + q0 * 8;
    const __bf16* pa1 = A + (size_t)(bm + sr1) * K + kbase + q1 * 8;
    const __bf16* pw0 = W + (size_t)(bn + sr0) * K + kbase + q0 * 8;
    const __bf16* pw1 = W + (size_t)(bn + sr1) * K + kbase + q1 * 8;
    const int dst0 = wave * 32 * 32;                 // elem offset (row*32)
    const int dst1 = dst0 + 16 * 32;

    // ---- fragment addressing ------------------------------------------------
    const int lr  = lane & 15;
    const int kq  = lane >> 4;
    const int ksw = (kq ^ ((lr >> 1) & 3)) * 8;      // swizzled chunk (elems)
    const int arow = wr * 128 + lr;                  // A frag row base
    const int wrow = wc * 64 + lr;                   // W frag row base

    floatx4 acc[8][4] = {};

    // ---- prologue: stage slabs 0,1,2 (12 loads/wave), need slab 0 ----------
    gload_lds16(pa0,       &As[dst0]);
    gload_lds16(pa1,       &As[dst1]);
    gload_lds16(pw0,       &Ws[dst0]);
    gload_lds16(pw1,       &Ws[dst1]);
    gload_lds16(pa0 + 32,  &As[SLAB + dst0]);
    gload_lds16(pa1 + 32,  &As[SLAB + dst1]);
    gload_lds16(pw0 + 32,  &Ws[SLAB + dst0]);
    gload_lds16(pw1 + 32,  &Ws[SLAB + dst1]);
    gload_lds16(pa0 + 64,  &As[2 * SLAB + dst0]);
    gload_lds16(pa1 + 64,  &As[2 * SLAB + dst1]);
    gload_lds16(pw0 + 64,  &Ws[2 * SLAB + dst0]);
    gload_lds16(pw1 + 64,  &Ws[2 * SLAB + dst1]);
    asm volatile("s_waitcnt vmcnt(8)" ::: "memory");   // slab 0 landed
    __builtin_amdgcn_s_barrier();
    __builtin_amdgcn_sched_barrier(0);

    // One K-slab = 2 phases. Phase 0: read wf[4]+af[4] (m-half 0), stage 2 A
    // loads, barrier, 16 MFMA. Phase 1: read af[4] (m-half 1), stage 2 W
    // loads, barrier, 16 MFMA, VM wait, barrier.
#define STEP_BODY(S, DOSTAGE, VMWAIT)                                        \
    {                                                                        \
        const int sl = ((S) & 3) * SLAB;                                     \
        bf16x8 wf[4], af[4];                                                 \
        _Pragma("unroll") for (int nt = 0; nt < 4; ++nt)                     \
            wf[nt] = *(const bf16x8*)&Ws[sl + (wrow + nt * 16) * 32 + ksw];  \
        _Pragma("unroll") for (int mt = 0; mt < 4; ++mt)                     \
            af[mt] = *(const bf16x8*)&As[sl + (arow + mt * 16) * 32 + ksw];  \
        if (DOSTAGE) {                                                       \
            const int sd = (S) + 3;                                          \
            const int dsl = (sd & 3) * SLAB;                                 \
            gload_lds16(pa0 + (size_t)sd * 32, &As[dsl + dst0]);             \
            gload_lds16(pa1 + (size_t)sd * 32, &As[dsl + dst1]);             \
        }                                                                    \
        __builtin_amdgcn_s_barrier();                                        \
        __builtin_amdgcn_sched_barrier(0);                                   \
        __builtin_amdgcn_s_setprio(1);                                       \
        _Pragma("unroll") for (int mt = 0; mt < 4; ++mt)                     \
            _Pragma("unroll") for (int nt = 0; nt < 4; ++nt)                 \
                acc[mt][nt] = __builtin_amdgcn_mfma_f32_16x16x32_bf16(       \
                    af[mt], wf[nt], acc[mt][nt], 0, 0, 0);                   \
        __builtin_amdgcn_s_setprio(0);                                       \
        __builtin_amdgcn_sched_barrier(0);                                   \
        __builtin_amdgcn_s_barrier();                                        \
        __builtin_amdgcn_sched_barrier(0);                                   \
        _Pragma("unroll") for (int mt = 0; mt < 4; ++mt)                     \
            af[mt] = *(const bf16x8*)&As[sl + (arow + 64 + mt * 16) * 32 + ksw]; \
        if (DOSTAGE) {                                                       \
            const int sd = (S) + 3;                                          \
            const int dsl = (sd & 3) * SLAB;                                 \
            gload_lds16(pw0 + (size_t)sd * 32, &Ws[dsl + dst0]);             \
            gload_lds16(pw1 + (size_t)sd * 32, &Ws[dsl + dst1]);             \
        }                                                                    \
        __builtin_amdgcn_s_barrier();                                        \
        __builtin_amdgcn_sched_barrier(0);                                   \
        __builtin_amdgcn_s_setprio(1);                                       \
        _Pragma("unroll") for (int mt = 0; mt < 4; ++mt)                     \
            _Pragma("unroll") for (int nt = 0; nt < 4; ++nt)                 \
                acc[4 + mt][nt] = __builtin_amdgcn_mfma_f32_16x16x32_bf16(   \
                    af[mt], wf[nt], acc[4 + mt][nt], 0, 0, 0);               \
        __builtin_amdgcn_s_setprio(0);                                       \
        __builtin_amdgcn_sched_barrier(0);                                   \
        VMWAIT;                                                              \
        __builtin_amdgcn_s_barrier();                                        \
        __builtin_amdgcn_sched_barrier(0);                                   \
    }

    int s = 0;
#pragma unroll 1
    for (; s < NKs - 3; ++s) {
        STEP_BODY(s, true, asm volatile("s_waitcnt vmcnt(8)" ::: "memory"))
    }
    STEP_BODY(s, false, asm volatile("s_waitcnt vmcnt(4)" ::: "memory")); ++s;
    STEP_BODY(s, false, asm volatile("s_waitcnt vmcnt(0)" ::: "memory")); ++s;
    STEP_BODY(s, false, (void)0);
#undef STEP_BODY

    // C/D layout: col = lane&15, row = (lane>>4)*4 + reg
    float* Cz = Cout + (size_t)zt * M * N;
    const int col = lane & 15;
    const int rq  = (lane >> 4) * 4;
#pragma unroll
    for (int mf = 0; mf < 8; ++mf) {
#pragma unroll
        for (int nt = 0; nt < 4; ++nt) {
            int n = bn + wc * 64 + nt * 16 + col;
#pragma unroll
            for (int rg = 0; rg < 4; ++rg) {
                int m = bm + wr * 128 + mf * 16 + rq + rg;
                Cz[(size_t)m * N + n] = acc[mf][nt][rg];
            }
        }
    }
}

// ----------------- 128x128 MFMA GEMM (dense epilogue) ----------------------
__global__ __launch_bounds__(256) void gemm_dense(
    const __bf16* __restrict__ A, const __bf16* __restrict__ W,
    float* __restrict__ Cout, const float* __restrict__ bias,
    int M, int N, int K) {
    constexpr int BK = 32;
    __shared__ __bf16 As[2][128 * BK];
    __shared__ __bf16 Ws[2][128 * BK];

    const int tid  = threadIdx.x;
    const int lane = tid & 63;
    const int wave = tid >> 6;

    const int id    = blockIdx.y * gridDim.x + blockIdx.x;
    const int mslab = gridDim.y >> 3;
    const int xcd   = id & 7;
    const int local = id >> 3;
    const int m_off = local % mslab;
    const int ntile = local / mslab;
    const int bm    = (xcd * mslab + m_off) * 128;
    const int bn    = ntile * 128;

    const int wm = (wave >> 1) * 64;
    const int wn = (wave & 1) * 64;
    const int lr = lane & 15;
    const int kq = lane >> 4;
    const int kssw = (kq ^ ((lr >> 1) & 3)) * 8;

    floatx4 acc[4][4] = {};

    auto stage = [&](int buf, int kpos) {
#pragma unroll
        for (int i = 0; i < 2; ++i) {
            int c = i * 256 + tid;
            int r = c >> 2;
            int q = (c & 3) ^ ((r >> 1) & 3);
            gload_lds16(&A[(size_t)(bm + r) * K + kpos + q * 8],
                        &As[buf][(size_t)(i * 256 + wave * 64) * 8]);
            gload_lds16(&W[(size_t)(bn + r) * K + kpos + q * 8],
                        &Ws[buf][(size_t)(i * 256 + wave * 64) * 8]);
        }
    };

    auto compute = [&](int buf) {
        bf16x8 af[4], wf[4];
#pragma unroll
        for (int t = 0; t < 4; ++t) {
            af[t] = *(const bf16x8*)&As[buf][(wm + t * 16 + lr) * BK + kssw];
            wf[t] = *(const bf16x8*)&Ws[buf][(wn + t * 16 + lr) * BK + kssw];
        }
#pragma unroll
        for (int mt = 0; mt < 4; ++mt)
#pragma unroll
            for (int nt = 0; nt < 4; ++nt)
                acc[mt][nt] = __builtin_amdgcn_mfma_f32_16x16x32_bf16(
                    af[mt], wf[nt], acc[mt][nt], 0, 0, 0);
    };

    stage(0, 0);
    for (int k0 = 0; k0 < K; k0 += 2 * BK) {
        __syncthreads();
        if (k0 + BK < K) stage(1, k0 + BK);
        compute(0);
        __syncthreads();
        if (k0 + 2 * BK < K) stage(0, k0 + 2 * BK);
        compute(1);
    }

    const int col = lane & 15;
    const int rquad = (lane >> 4) * 4;
#pragma unroll
    for (int mt = 0; mt < 4; ++mt) {
#pragma unroll
        for (int nt = 0; nt < 4; ++nt) {
            int n = bn + wn + nt * 16 + col;
#pragma unroll
            for (int rg = 0; rg < 4; ++rg) {
                int m = bm + wm + mt * 16 + rquad + rg;
                Cout[(size_t)m * N + n] = acc[mt][nt][rg] + bias[n];
            }
        }
    }
}

// ---------------------------------------------------------------------------
extern "C" void kernel_launch(void* const* d_in, const int* in_sizes, int n_in,
                              void* d_out, int out_size, void* d_ws, size_t ws_size,
                              hipStream_t stream) {
    const float* x   = (const float*)d_in[0];
    const float* bw0 = (const float*)d_in[1];
    const float* sw0 = (const float*)d_in[2];
    const float* ss0 = (const float*)d_in[3];
    const float* bw1 = (const float*)d_in[4];
    const float* sw1 = (const float*)d_in[5];
    const float* ss1 = (const float*)d_in[6];
    const float* dw  = (const float*)d_in[7];
    const float* db  = (const float*)d_in[8];
    float* out = (float*)d_out;

    char* ws = (char*)d_ws;
    __bf16* A0  = (__bf16*)(ws + OFF_A0);
    __bf16* W0  = (__bf16*)(ws + OFF_W0);
    __bf16* A1  = (__bf16*)(ws + OFF_A1);
    float*  P0  = (float*)(ws + OFF_P0);
    __bf16* W1  = (__bf16*)(ws + OFF_W1);
    float*  P1  = (float*)(ws + OFF_P1);
    __bf16* h1r = (__bf16*)(ws + OFF_H1R);
    __bf16* dwb = (__bf16*)(ws + OFF_DW);

    // Layer 0: K = 9216, splitK=2 -> grid 8x16x2 = 256 blocks (1/CU)
    kan_wprep<<<(H0N * DIN) / 256, 256, 0, stream>>>(bw0, sw0, ss0, W0);
    kan_act<<<(BATCH * DIN) / 256, 256, 0, stream>>>(x, A0);
    gemm8<<<dim3(H0N / 256, BATCH / 256, 2), 512, 0, stream>>>(
        A0, W0, P0, BATCH, H0N, DIN * 9, DIN * 9 / 2);

    // Layer 1: K = 18432, splitK=4 -> grid 4x16x4 = 256 blocks (1/CU)
    kan_wprep<<<(H1N * H0N) / 256, 256, 0, stream>>>(bw1, sw1, ss1, W1);
    kan_act_sum2<<<(BATCH * H0N) / 256, 256, 0, stream>>>(
        P0, P0 + (size_t)BATCH * H0N, A1);
    gemm8<<<dim3(H1N / 256, BATCH / 256, 4), 512, 0, stream>>>(
        A1, W1, P1, BATCH, H1N, H0N * 9, H0N * 9 / 4);

    // relu(sum of 4 partials) -> bf16
    relu_sum4<<<(BATCH * H1N / 4) / 256, 256, 0, stream>>>(
        P1, (size_t)BATCH * H1N, h1r, BATCH * H1N / 4);

    // Dense: out = h1r @ dw^T + db  (K = 1024)
    f2bf<<<(LOUT * H1N) / 256, 256, 0, stream>>>(dw, dwb, LOUT * H1N);
    gemm_dense<<<dim3(LOUT / 128, BATCH / 128), 256, 0, stream>>>(
        h1r, dwb, out, db, BATCH, LOUT, H1N);
}

// Round 2
// 614.536 us; speedup vs baseline: 1.0480x; 1.0480x over previous
//
#include <hip/hip_runtime.h>
#include <cstdint>
#include <cstddef>

// ---------------------------------------------------------------------------
// KAN encode: x(4096,1024) -> KANLinear(1024->2048) -> KANLinear(2048->1024)
//             -> ReLU -> Dense(1024->512)+bias
// bf16 MFMA GEMMs over augmented K (9 channels per input feature).
// R9: R8's 256x256 1-block/CU lockstep schedule regressed (32% MfmaUtil) —
//     it gave up gemm_big's 2-blocks/CU inter-block overlap. Revert to the
//     proven 256x128 / 4-wave / 2-blocks-per-CU structure and remove ONLY
//     the documented ~20% stall: __syncthreads()'s vmcnt(0) drain.
//       - 3-deep cyclic LDS (A 3x16K + W 3x8K = 72 KB; 2 blocks still fit)
//       - one raw s_barrier per K-step (was 2), counted s_waitcnt vmcnt(6)
//         lgkmcnt(0) per step (stage slab s+2 while computing slab s;
//         6 loads stay in flight across the barrier; epilogue drains 6->0)
//       - s_setprio(1) around the 32-MFMA cluster (2 desynced blocks/CU =
//         real arbitration)
//       - proven 0-conflict XOR swizzle q = p ^ ((r>>1)&3) unchanged
// ---------------------------------------------------------------------------

typedef __bf16 bf16x8 __attribute__((ext_vector_type(8)));
typedef float floatx4 __attribute__((ext_vector_type(4)));

#define BATCH 4096
#define DIN   1024
#define H0N   2048
#define H1N   1024
#define LOUT  512

// Workspace layout (bytes). Total = 227,540,992.
#define OFF_A0  ((size_t)0)           // bf16 4096*9216  = 75,497,472
#define OFF_W0  ((size_t)75497472)    // bf16 2048*9216  = 37,748,736
#define OFF_A1  ((size_t)0)           // bf16 4096*18432 = 150,994,944 (overlays A0+W0)
#define OFF_P0  ((size_t)150994944)   // f32 2*4096*2048 = 67,108,864
#define OFF_W1  ((size_t)218103808)   // bf16 1024*18432 = 37,748,736
#define OFF_P1  ((size_t)150994944)   // f32 4*4096*1024 = 67,108,864 (overlays P0)
#define OFF_H1R ((size_t)218103808)   // bf16 4096*1024  =  8,388,608 (overlays W1)
#define OFF_DW  ((size_t)226492416)   // bf16 512*1024   =  1,048,576

// --------------------------- spline bases ----------------------------------
__device__ __forceinline__ void bspline8(float x, float* out) {
    float b[11];
#pragma unroll
    for (int j = 0; j < 11; ++j) {
        float t0 = (j - 3) * 0.4f - 1.0f;
        float t1 = (j - 2) * 0.4f - 1.0f;
        b[j] = (x >= t0 && x < t1) ? 1.0f : 0.0f;
    }
#pragma unroll
    for (int k = 1; k <= 3; ++k) {
#pragma unroll
        for (int j = 0; j + k < 11; ++j) {
            float tj   = (j - 3) * 0.4f - 1.0f;
            float tj1  = (j - 2) * 0.4f - 1.0f;
            float tjk  = (j + k - 3) * 0.4f - 1.0f;
            float tjk1 = (j + k - 2) * 0.4f - 1.0f;
            float left  = (x - tj)   * (1.0f / (tjk - tj));
            float right = (tjk1 - x) * (1.0f / (tjk1 - tj1));
            b[j] = left * b[j] + right * b[j + 1];
        }
    }
#pragma unroll
    for (int j = 0; j < 8; ++j) out[j] = b[j];
}

// Store 256 threads * 9 bf16 via LDS as 288 coalesced 16B chunks.
__device__ __forceinline__ void coalesced_store9(__bf16* block_dst, const __bf16* vals) {
    __shared__ __bf16 sbuf[256 * 9];
    __bf16* p = &sbuf[threadIdx.x * 9];
#pragma unroll
    for (int j = 0; j < 9; ++j) p[j] = vals[j];
    __syncthreads();
    const uint4* src = (const uint4*)sbuf;
    uint4* dst = (uint4*)block_dst;
    dst[threadIdx.x] = src[threadIdx.x];
    if (threadIdx.x < 32) dst[256 + threadIdx.x] = src[256 + threadIdx.x];
}

__device__ __forceinline__ void act9(float v, __bf16* r) {
    float s = v / (1.0f + __expf(-v));
    float bb[8];
    bspline8(v, bb);
    r[0] = (__bf16)s;
#pragma unroll
    for (int j = 0; j < 8; ++j) r[1 + j] = (__bf16)bb[j];
}

__global__ void kan_act(const float* __restrict__ in, __bf16* __restrict__ out) {
    int base = blockIdx.x * 256;
    float v = in[base + threadIdx.x];
    __bf16 r[9];
    act9(v, r);
    coalesced_store9(out + (size_t)base * 9, r);
}

__global__ void kan_act_sum2(const float* __restrict__ pa, const float* __restrict__ pb,
                             __bf16* __restrict__ out) {
    int base = blockIdx.x * 256;
    int idx = base + threadIdx.x;
    float v = pa[idx] + pb[idx];
    __bf16 r[9];
    act9(v, r);
    coalesced_store9(out + (size_t)base * 9, r);
}

__global__ void relu_sum4(const float* __restrict__ p, size_t stride,
                          __bf16* __restrict__ out, int total4) {
    int idx = blockIdx.x * 256 + threadIdx.x;
    if (idx >= total4) return;
    const float4* p0 = (const float4*)p;
    const float4* p1 = (const float4*)(p + stride);
    const float4* p2 = (const float4*)(p + 2 * stride);
    const float4* p3 = (const float4*)(p + 3 * stride);
    float4 a = p0[idx], b = p1[idx], c = p2[idx], d = p3[idx];
    __bf16 r[4];
    r[0] = (__bf16)fmaxf(a.x + b.x + c.x + d.x, 0.0f);
    r[1] = (__bf16)fmaxf(a.y + b.y + c.y + d.y, 0.0f);
    r[2] = (__bf16)fmaxf(a.z + b.z + c.z + d.z, 0.0f);
    r[3] = (__bf16)fmaxf(a.w + b.w + c.w + d.w, 0.0f);
    *(uint2*)&out[(size_t)idx * 4] = *(uint2*)r;
}

__global__ void kan_wprep(const float* __restrict__ bw, const float* __restrict__ sw,
                          const float* __restrict__ ss, __bf16* __restrict__ out) {
    int base = blockIdx.x * 256;
    int idx = base + threadIdx.x;
    float b  = bw[idx];
    float sc = ss[idx];
    const float4* sv = (const float4*)(sw + (size_t)idx * 8);
    float4 a = sv[0], c = sv[1];
    __bf16 r[9];
    r[0] = (__bf16)b;
    r[1] = (__bf16)(a.x * sc); r[2] = (__bf16)(a.y * sc);
    r[3] = (__bf16)(a.z * sc); r[4] = (__bf16)(a.w * sc);
    r[5] = (__bf16)(c.x * sc); r[6] = (__bf16)(c.y * sc);
    r[7] = (__bf16)(c.z * sc); r[8] = (__bf16)(c.w * sc);
    coalesced_store9(out + (size_t)base * 9, r);
}

__global__ void f2bf(const float* __restrict__ in, __bf16* __restrict__ out,
                     int total) {
    int idx = blockIdx.x * 256 + threadIdx.x;
    if (idx < total) out[idx] = (__bf16)in[idx];
}

// --------------------------- staging helper --------------------------------
__device__ __forceinline__ void gload_lds16(const void* g, void* l) {
    __builtin_amdgcn_global_load_lds(
        (const __attribute__((address_space(1))) uint32_t*)g,
        (__attribute__((address_space(3))) uint32_t*)l, 16, 0, 0);
}

// Bank swizzle: LDS slot (row r, pos p) holds global chunk q = p ^ ((r>>1)&3).
// Frag reads (rows base+lr, lr=0..15, chunk kq) land 2 lanes per 4-bank group
// -> 2-way aliasing = free (verified: SQ_LDS_BANK_CONFLICT == 0).

// ---- pipelined MFMA GEMM: 256x128 tile, 4 waves (64x128 each), 2 blk/CU ---
// C(M,N) = A(M,K) @ W(N,K)^T, bf16 in, fp32 out (split-K partial per z).
// 3-deep cyclic LDS; per K-step: {stage slab s+2 | reads(s) | 32 MFMA |
// s_waitcnt vmcnt(6) lgkmcnt(0) | s_barrier}. vmcnt never drains to 0 in
// the main loop (6 loads = next stage stay in flight across the barrier).
__global__ __launch_bounds__(256, 2) void gemm_pipe(
    const __bf16* __restrict__ A, const __bf16* __restrict__ W,
    float* __restrict__ Cout, int M, int N, int K, int Ks) {
    constexpr int BK = 32;                    // 64 B LDS rows (4 x 16B chunks)
    __shared__ __bf16 As[3][256 * BK];        // 3 x 16 KB
    __shared__ __bf16 Ws[3][128 * BK];        // 3 x 8 KB

    const int tid  = threadIdx.x;
    const int lane = tid & 63;
    const int wave = tid >> 6;

    // XCD-aware swizzle (round-robin dispatch: id&7 = XCD)
    const int id    = (blockIdx.z * gridDim.y + blockIdx.y) * gridDim.x + blockIdx.x;
    const int mslab = gridDim.y >> 3;
    const int xcd   = id & 7;
    const int local = id >> 3;
    const int m_off = local % mslab;
    const int rest  = local / mslab;
    const int ntile = rest % gridDim.x;
    const int zt    = rest / gridDim.x;
    const int bm    = (xcd * mslab + m_off) * 256;
    const int bn    = ntile * 128;
    const int kbase = zt * Ks;

    const int wm = wave * 64;
    const int lr = lane & 15;
    const int kq = lane >> 4;                      // k-chunk 0..3
    const int kssw = (kq ^ ((lr >> 1) & 3)) * 8;   // swizzled frag chunk offset

    floatx4 acc[4][8] = {};

    auto stage = [&](int slot, int kstep) {
        const int kpos = kstep * BK;
#pragma unroll
        for (int i = 0; i < 4; ++i) {          // A: 1024 chunks of 16 B
            int c = i * 256 + tid;
            int r = c >> 2;
            int q = (c & 3) ^ ((r >> 1) & 3);  // swizzled source chunk
            gload_lds16(&A[(size_t)(bm + r) * K + kbase + kpos + q * 8],
                        &As[slot][(size_t)(i * 256 + wave * 64) * 8]);
        }
#pragma unroll
        for (int i = 0; i < 2; ++i) {          // W: 512 chunks
            int c = i * 256 + tid;
            int r = c >> 2;
            int q = (c & 3) ^ ((r >> 1) & 3);
            gload_lds16(&W[(size_t)(bn + r) * K + kbase + kpos + q * 8],
                        &Ws[slot][(size_t)(i * 256 + wave * 64) * 8]);
        }
    };

    auto compute = [&](int slot) {
        bf16x8 af[4], wf[8];
#pragma unroll
        for (int t = 0; t < 4; ++t)
            af[t] = *(const bf16x8*)&As[slot][(wm + t * 16 + lr) * BK + kssw];
#pragma unroll
        for (int t = 0; t < 8; ++t)
            wf[t] = *(const bf16x8*)&Ws[slot][(t * 16 + lr) * BK + kssw];
        __builtin_amdgcn_s_setprio(1);
#pragma unroll
        for (int mt = 0; mt < 4; ++mt)
#pragma unroll
            for (int nt = 0; nt < 8; ++nt)
                acc[mt][nt] = __builtin_amdgcn_mfma_f32_16x16x32_bf16(
                    af[mt], wf[nt], acc[mt][nt], 0, 0, 0);
        __builtin_amdgcn_s_setprio(0);
    };

    const int NKs = Ks >> 5;                  // 32-wide K-steps (144)

    // Prologue: stage slabs 0,1 (12 loads/wave); need slab 0 -> vmcnt(6).
    stage(0, 0);
    stage(1, 1);
    asm volatile("s_waitcnt vmcnt(6)" ::: "memory");
    __builtin_amdgcn_s_barrier();

    int sl = 0;
#pragma unroll 1
    for (int s = 0; s < NKs - 2; ++s) {
        int sln = sl + 2; if (sln >= 3) sln -= 3;
        stage(sln, s + 2);                    // DMA issues first, hides under compute
        compute(sl);
        // slab s+1 must be landed; stage(s+2)'s 6 loads stay in flight.
        asm volatile("s_waitcnt vmcnt(6) lgkmcnt(0)" ::: "memory");
        __builtin_amdgcn_s_barrier();
        sl = (sl == 2) ? 0 : sl + 1;
    }
    compute(sl);
    asm volatile("s_waitcnt vmcnt(0) lgkmcnt(0)" ::: "memory");
    __builtin_amdgcn_s_barrier();
    sl = (sl == 2) ? 0 : sl + 1;
    compute(sl);

    // C/D layout: col = lane&15, row = (lane>>4)*4 + reg
    float* Cz = Cout + (size_t)zt * M * N;
    const int col = lane & 15;
    const int rquad = (lane >> 4) * 4;
#pragma unroll
    for (int mt = 0; mt < 4; ++mt) {
#pragma unroll
        for (int nt = 0; nt < 8; ++nt) {
            int n = bn + nt * 16 + col;
#pragma unroll
            for (int rg = 0; rg < 4; ++rg) {
                int m = bm + wm + mt * 16 + rquad + rg;
                Cz[(size_t)m * N + n] = acc[mt][nt][rg];
            }
        }
    }
}

// ----------------- 128x128 MFMA GEMM (dense epilogue) ----------------------
__global__ __launch_bounds__(256) void gemm_dense(
    const __bf16* __restrict__ A, const __bf16* __restrict__ W,
    float* __restrict__ Cout, const float* __restrict__ bias,
    int M, int N, int K) {
    constexpr int BK = 32;
    __shared__ __bf16 As[2][128 * BK];
    __shared__ __bf16 Ws[2][128 * BK];

    const int tid  = threadIdx.x;
    const int lane = tid & 63;
    const int wave = tid >> 6;

    const int id    = blockIdx.y * gridDim.x + blockIdx.x;
    const int mslab = gridDim.y >> 3;
    const int xcd   = id & 7;
    const int local = id >> 3;
    const int m_off = local % mslab;
    const int ntile = local / mslab;
    const int bm    = (xcd * mslab + m_off) * 128;
    const int bn    = ntile * 128;

    const int wm = (wave >> 1) * 64;
    const int wn = (wave & 1) * 64;
    const int lr = lane & 15;
    const int kq = lane >> 4;
    const int kssw = (kq ^ ((lr >> 1) & 3)) * 8;

    floatx4 acc[4][4] = {};

    auto stage = [&](int buf, int kpos) {
#pragma unroll
        for (int i = 0; i < 2; ++i) {
            int c = i * 256 + tid;
            int r = c >> 2;
            int q = (c & 3) ^ ((r >> 1) & 3);
            gload_lds16(&A[(size_t)(bm + r) * K + kpos + q * 8],
                        &As[buf][(size_t)(i * 256 + wave * 64) * 8]);
            gload_lds16(&W[(size_t)(bn + r) * K + kpos + q * 8],
                        &Ws[buf][(size_t)(i * 256 + wave * 64) * 8]);
        }
    };

    auto compute = [&](int buf) {
        bf16x8 af[4], wf[4];
#pragma unroll
        for (int t = 0; t < 4; ++t) {
            af[t] = *(const bf16x8*)&As[buf][(wm + t * 16 + lr) * BK + kssw];
            wf[t] = *(const bf16x8*)&Ws[buf][(wn + t * 16 + lr) * BK + kssw];
        }
#pragma unroll
        for (int mt = 0; mt < 4; ++mt)
#pragma unroll
            for (int nt = 0; nt < 4; ++nt)
                acc[mt][nt] = __builtin_amdgcn_mfma_f32_16x16x32_bf16(
                    af[mt], wf[nt], acc[mt][nt], 0, 0, 0);
    };

    stage(0, 0);
    for (int k0 = 0; k0 < K; k0 += 2 * BK) {
        __syncthreads();
        if (k0 + BK < K) stage(1, k0 + BK);
        compute(0);
        __syncthreads();
        if (k0 + 2 * BK < K) stage(0, k0 + 2 * BK);
        compute(1);
    }

    const int col = lane & 15;
    const int rquad = (lane >> 4) * 4;
#pragma unroll
    for (int mt = 0; mt < 4; ++mt) {
#pragma unroll
        for (int nt = 0; nt < 4; ++nt) {
            int n = bn + wn + nt * 16 + col;
#pragma unroll
            for (int rg = 0; rg < 4; ++rg) {
                int m = bm + wm + mt * 16 + rquad + rg;
                Cout[(size_t)m * N + n] = acc[mt][nt][rg] + bias[n];
            }
        }
    }
}

// ---------------------------------------------------------------------------
extern "C" void kernel_launch(void* const* d_in, const int* in_sizes, int n_in,
                              void* d_out, int out_size, void* d_ws, size_t ws_size,
                              hipStream_t stream) {
    const float* x   = (const float*)d_in[0];
    const float* bw0 = (const float*)d_in[1];
    const float* sw0 = (const float*)d_in[2];
    const float* ss0 = (const float*)d_in[3];
    const float* bw1 = (const float*)d_in[4];
    const float* sw1 = (const float*)d_in[5];
    const float* ss1 = (const float*)d_in[6];
    const float* dw  = (const float*)d_in[7];
    const float* db  = (const float*)d_in[8];
    float* out = (float*)d_out;

    char* ws = (char*)d_ws;
    __bf16* A0  = (__bf16*)(ws + OFF_A0);
    __bf16* W0  = (__bf16*)(ws + OFF_W0);
    __bf16* A1  = (__bf16*)(ws + OFF_A1);
    float*  P0  = (float*)(ws + OFF_P0);
    __bf16* W1  = (__bf16*)(ws + OFF_W1);
    float*  P1  = (float*)(ws + OFF_P1);
    __bf16* h1r = (__bf16*)(ws + OFF_H1R);
    __bf16* dwb = (__bf16*)(ws + OFF_DW);

    // Layer 0: K = 9216, splitK=2 -> grid 16x16x2 = 512 blocks (2/CU)
    kan_wprep<<<(H0N * DIN) / 256, 256, 0, stream>>>(bw0, sw0, ss0, W0);
    kan_act<<<(BATCH * DIN) / 256, 256, 0, stream>>>(x, A0);
    gemm_pipe<<<dim3(H0N / 128, BATCH / 256, 2), 256, 0, stream>>>(
        A0, W0, P0, BATCH, H0N, DIN * 9, DIN * 9 / 2);

    // Layer 1: K = 18432, splitK=4 -> grid 8x16x4 = 512 blocks (2/CU)
    kan_wprep<<<(H1N * H0N) / 256, 256, 0, stream>>>(bw1, sw1, ss1, W1);
    kan_act_sum2<<<(BATCH * H0N) / 256, 256, 0, stream>>>(
        P0, P0 + (size_t)BATCH * H0N, A1);
    gemm_pipe<<<dim3(H1N / 128, BATCH / 256, 4), 256, 0, stream>>>(
        A1, W1, P1, BATCH, H1N, H0N * 9, H0N * 9 / 4);

    // relu(sum of 4 partials) -> bf16
    relu_sum4<<<(BATCH * H1N / 4) / 256, 256, 0, stream>>>(
        P1, (size_t)BATCH * H1N, h1r, BATCH * H1N / 4);

    // Dense: out = h1r @ dw^T + db  (K = 1024)
    f2bf<<<(LOUT * H1N) / 256, 256, 0, stream>>>(dw, dwb, LOUT * H1N);
    gemm_dense<<<dim3(LOUT / 128, BATCH / 128), 256, 0, stream>>>(
        h1r, dwb, out, db, BATCH, LOUT, H1N);
}